// Round 1
// baseline (397.781 us; speedup 1.0000x reference)
//
#include <hip/hip_runtime.h>
#include <math.h>

#define STATE 24
#define L1N 100
#define L2N 100
#define ACT 6
#define CHOLN 21

// One thread = one batch row. x1 held in VGPRs; layer-2 fused with both
// heads so x2 is never materialized (27 head FMAs per x2 element).
// All weight reads are wave-uniform -> compiler emits s_load (scalar cache),
// co-issuing with the v_fma_f32 stream. fp32 throughout (VALU-bound ~50us
// floor); bf16 MFMA is the planned next step.
__global__ __launch_bounds__(256) void actor_fwd(
    const float* __restrict__ states,
    const float* __restrict__ W1, const float* __restrict__ b1,
    const float* __restrict__ W2, const float* __restrict__ b2,
    const float* __restrict__ Wm, const float* __restrict__ bm,
    const float* __restrict__ Wc, const float* __restrict__ bc,
    float* __restrict__ out_mean,   // [B, 6]
    float* __restrict__ out_chol,   // [B, 6, 6]
    int batch)
{
    const int b = blockIdx.x * blockDim.x + threadIdx.x;
    if (b >= batch) return;

    // ---- load state row (24 floats = 6x float4) ----
    float s[STATE];
    const float4* sp = (const float4*)(states + (size_t)b * STATE);
    #pragma unroll
    for (int k = 0; k < STATE / 4; ++k) {
        float4 v = sp[k];
        s[4*k+0] = v.x; s[4*k+1] = v.y; s[4*k+2] = v.z; s[4*k+3] = v.w;
    }

    // ---- layer 1: x1 = relu(W1 @ s + b1) ----
    float x1[L1N];
    #pragma unroll 4
    for (int i = 0; i < L1N; ++i) {
        float acc = b1[i];
        #pragma unroll
        for (int k = 0; k < STATE; ++k)
            acc = fmaf(s[k], W1[i * STATE + k], acc);
        x1[i] = fmaxf(acc, 0.0f);
    }

    // ---- layer 2 fused with heads ----
    float m_acc[ACT];
    float c_acc[CHOLN];
    #pragma unroll
    for (int k = 0; k < ACT; ++k)  m_acc[k] = bm[k];
    #pragma unroll
    for (int c = 0; c < CHOLN; ++c) c_acc[c] = bc[c];

    #pragma unroll 2
    for (int j = 0; j < L2N; ++j) {
        float acc = b2[j];
        #pragma unroll
        for (int i = 0; i < L1N; ++i)
            acc = fmaf(x1[i], W2[j * L1N + i], acc);
        float a = fmaxf(acc, 0.0f);   // x2[j]
        #pragma unroll
        for (int k = 0; k < ACT; ++k)
            m_acc[k] = fmaf(a, Wm[k * L2N + j], m_acc[k]);
        #pragma unroll
        for (int c = 0; c < CHOLN; ++c)
            c_acc[c] = fmaf(a, Wc[c * L2N + j], c_acc[c]);
    }

    // ---- mean head: tanh ----
    {
        float2* mp = (float2*)(out_mean + (size_t)b * ACT);
        #pragma unroll
        for (int k = 0; k < ACT / 2; ++k)
            mp[k] = make_float2(tanhf(m_acc[2*k]), tanhf(m_acc[2*k+1]));
    }

    // ---- chol head: softplus into lower-triangular 6x6 ----
    float ch[36];
    #pragma unroll
    for (int i = 0; i < 36; ++i) ch[i] = 0.0f;
    {
        int c = 0;
        #pragma unroll
        for (int i = 0; i < ACT; ++i) {
            #pragma unroll
            for (int j = 0; j <= i; ++j) {
                float v = c_acc[c++];
                // numerically-stable softplus: max(v,0) + log1p(exp(-|v|))
                ch[i * ACT + j] = fmaxf(v, 0.0f) + log1pf(expf(-fabsf(v)));
            }
        }
    }
    float4* cp = (float4*)(out_chol + (size_t)b * 36);
    #pragma unroll
    for (int i = 0; i < 9; ++i)
        cp[i] = make_float4(ch[4*i], ch[4*i+1], ch[4*i+2], ch[4*i+3]);
}

extern "C" void kernel_launch(void* const* d_in, const int* in_sizes, int n_in,
                              void* d_out, int out_size, void* d_ws, size_t ws_size,
                              hipStream_t stream) {
    const float* states = (const float*)d_in[0];
    const float* W1 = (const float*)d_in[1];
    const float* b1 = (const float*)d_in[2];
    const float* W2 = (const float*)d_in[3];
    const float* b2 = (const float*)d_in[4];
    const float* Wm = (const float*)d_in[5];
    const float* bm = (const float*)d_in[6];
    const float* Wc = (const float*)d_in[7];
    const float* bc = (const float*)d_in[8];

    const int batch = in_sizes[0] / STATE;          // 262144
    float* out_mean = (float*)d_out;                // [B,6] flat first
    float* out_chol = (float*)d_out + (size_t)batch * ACT;  // then [B,6,6]

    const int block = 256;
    const int grid = (batch + block - 1) / block;
    actor_fwd<<<grid, block, 0, stream>>>(states, W1, b1, W2, b2,
                                          Wm, bm, Wc, bc,
                                          out_mean, out_chol, batch);
}

// Round 2
// 168.105 us; speedup vs baseline: 2.3663x; 2.3663x over previous
//
#include <hip/hip_runtime.h>
#include <math.h>

typedef short bf16x8 __attribute__((ext_vector_type(8)));
typedef float f32x4 __attribute__((ext_vector_type(4)));

#define STATE 24
#define L1N 100
#define HN 27   // 6 mean + 21 chol head rows

// ---- LDS layout (ushort units) ----
// Strides: bytes multiple of 16 (b128-aligned) and (stride/16B) odd ->
// quarter-wave phases see <=2-way bank aliasing (free per m136).
#define W1_STRIDE 40      // K 24 -> pad 32, stride 40 halves = 80 B
#define K_STRIDE 136      // K 100 -> pad 128, stride 136 halves = 272 B
#define NROWS1 112        // 100 -> 7 n-tiles of 16
#define W1_HALVES (NROWS1 * W1_STRIDE)        // 4480
#define W2_HALVES (NROWS1 * K_STRIDE)         // 15232
#define WH_HALVES (32 * K_STRIDE)             // 4352
#define X_HALVES_PER_WAVE (32 * K_STRIDE)     // 4352 (32 rows x 136)
#define NWAVES 8
#define LDS_HALVES (W1_HALVES + W2_HALVES + WH_HALVES + NWAVES * X_HALVES_PER_WAVE)
#define LDS_BYTES (LDS_HALVES * 2)            // 117760 B < 160 KiB

// tril (row-major, j<=i) -> flat 6x6 offsets; and the 15 upper-tri offsets
__device__ __constant__ int CHOFF[21] = {0,6,7,12,13,14,18,19,20,21,24,25,26,27,28,30,31,32,33,34,35};
__device__ __constant__ int ZOFF[15]  = {1,2,3,4,5,8,9,10,11,15,16,17,22,23,29};

__device__ inline unsigned short f2bf(float f) {
    union { float f; unsigned u; } v; v.f = f;
    unsigned r = v.u + 0x7FFFu + ((v.u >> 16) & 1u);   // RNE
    return (unsigned short)(r >> 16);
}

// Convert a fp32 weight matrix [nSrc x kSrc] into zero-padded bf16 LDS
// [nRows x strideHalf], row-major, pairs packed as u32 writes.
__device__ inline void stage_w(unsigned* dst, const float* __restrict__ src,
                               int nRows, int strideHalf, int nSrc, int kSrc,
                               int tid, int nthr) {
    const int pairs = strideHalf >> 1;
    const int total = nRows * pairs;
    for (int idx = tid; idx < total; idx += nthr) {
        int n = idx / pairs;
        int p = idx - n * pairs;
        int k = p << 1;
        float lo = 0.f, hi = 0.f;
        if (n < nSrc) {
            if (k < kSrc)     lo = src[n * kSrc + k];
            if (k + 1 < kSrc) hi = src[n * kSrc + k + 1];
        }
        dst[n * pairs + p] = (unsigned)f2bf(lo) | ((unsigned)f2bf(hi) << 16);
    }
}

__global__ __launch_bounds__(512, 2) void actor_mfma(
    const float* __restrict__ states,
    const float* __restrict__ W1, const float* __restrict__ b1,
    const float* __restrict__ W2, const float* __restrict__ b2,
    const float* __restrict__ Wm, const float* __restrict__ bm,
    const float* __restrict__ Wc, const float* __restrict__ bc,
    float* __restrict__ out_mean, float* __restrict__ out_chol)
{
    extern __shared__ __align__(16) unsigned short smem[];
    unsigned short* W1s = smem;
    unsigned short* W2s = smem + W1_HALVES;
    unsigned short* Whs = W2s + W2_HALVES;
    unsigned short* Xs  = Whs + WH_HALVES;

    const int tid = threadIdx.x;
    // ---- stage weights fp32->bf16 into LDS (zero-padded) ----
    stage_w((unsigned*)W1s, W1, NROWS1, W1_STRIDE, L1N, STATE, tid, 512);
    stage_w((unsigned*)W2s, W2, NROWS1, K_STRIDE, L1N, L1N, tid, 512);
    stage_w((unsigned*)Whs, Wm, 6, K_STRIDE, 6, L1N, tid, 512);
    stage_w((unsigned*)(Whs + 6 * K_STRIDE), Wc, 26, K_STRIDE, 21, L1N, tid, 512);

    const int wave = tid >> 6;
    const int lane = tid & 63;
    unsigned short* XsW = Xs + wave * X_HALVES_PER_WAVE;
    {   // zero own-wave X buffer (K-pad cols 100..127 must be 0)
        uint2* xz = (uint2*)XsW;   // 4352 halves = 1088 u32 = 544 u64... use u64x17
        const uint2 z = make_uint2(0u, 0u);
        #pragma unroll
        for (int i = 0; i < X_HALVES_PER_WAVE / 4; i += 64)   // 1088/64 = 17
            xz[i + lane] = z;
    }
    __syncthreads();

    const int q = lane >> 4;      // quad 0..3
    const int c = lane & 15;      // col-in-tile / A-row / B-row index
    const size_t rowBase = (size_t)blockIdx.x * 256 + (size_t)wave * 32;

    // ---- GEMM1: x1 = relu(states @ W1^T + b1)  [32 x 100] ----
    // A-frag: lane holds A[m=c][k=q*8+j]; rows 96B apart, 16B-aligned loads.
    bf16x8 af[2];
    #pragma unroll
    for (int t = 0; t < 2; ++t) {
        bf16x8 a = {0,0,0,0,0,0,0,0};
        if (q < 3) {
            const float* p = states + (rowBase + t*16 + c) * STATE + q*8;
            float4 v0 = *(const float4*)p;
            float4 v1 = *(const float4*)(p + 4);
            a[0] = (short)f2bf(v0.x); a[1] = (short)f2bf(v0.y);
            a[2] = (short)f2bf(v0.z); a[3] = (short)f2bf(v0.w);
            a[4] = (short)f2bf(v1.x); a[5] = (short)f2bf(v1.y);
            a[6] = (short)f2bf(v1.z); a[7] = (short)f2bf(v1.w);
        }
        af[t] = a;
    }
    #pragma unroll
    for (int nt = 0; nt < 7; ++nt) {
        const int n = nt*16 + c;
        bf16x8 bf = *(const bf16x8*)&W1s[(nt*16 + c) * W1_STRIDE + q*8];
        const float bias = (n < L1N) ? b1[n] : 0.f;
        #pragma unroll
        for (int t = 0; t < 2; ++t) {
            f32x4 acc = {0.f, 0.f, 0.f, 0.f};
            acc = __builtin_amdgcn_mfma_f32_16x16x32_bf16(af[t], bf, acc, 0, 0, 0);
            if (n < L1N) {
                // C layout: row = q*4+i, col = c  -> Xs[row][n]
                #pragma unroll
                for (int i = 0; i < 4; ++i) {
                    float v = fmaxf(acc[i] + bias, 0.f);
                    XsW[(t*16 + q*4 + i) * K_STRIDE + n] = f2bf(v);
                }
            }
        }
    }
    // wave-private LDS: DS ops from one wave process in order; no sync needed

    // ---- GEMM2: x2 = relu(x1 @ W2^T + b2)  [32 x 100], K = 128 padded ----
    f32x4 acc2[2][7];
    #pragma unroll
    for (int t = 0; t < 2; ++t)
        #pragma unroll
        for (int nt = 0; nt < 7; ++nt)
            acc2[t][nt] = (f32x4){0.f, 0.f, 0.f, 0.f};
    #pragma unroll
    for (int ks = 0; ks < 4; ++ks) {
        bf16x8 a0 = *(const bf16x8*)&XsW[ c       * K_STRIDE + ks*32 + q*8];
        bf16x8 a1 = *(const bf16x8*)&XsW[(16 + c) * K_STRIDE + ks*32 + q*8];
        #pragma unroll
        for (int nt = 0; nt < 7; ++nt) {
            bf16x8 bf = *(const bf16x8*)&W2s[(nt*16 + c) * K_STRIDE + ks*32 + q*8];
            acc2[0][nt] = __builtin_amdgcn_mfma_f32_16x16x32_bf16(a0, bf, acc2[0][nt], 0, 0, 0);
            acc2[1][nt] = __builtin_amdgcn_mfma_f32_16x16x32_bf16(a1, bf, acc2[1][nt], 0, 0, 0);
        }
    }
    #pragma unroll
    for (int nt = 0; nt < 7; ++nt) {
        const int n = nt*16 + c;
        if (n < L1N) {
            const float bias = b2[n];
            #pragma unroll
            for (int t = 0; t < 2; ++t)
                #pragma unroll
                for (int i = 0; i < 4; ++i) {
                    float v = fmaxf(acc2[t][nt][i] + bias, 0.f);
                    XsW[(t*16 + q*4 + i) * K_STRIDE + n] = f2bf(v);
                }
        }
    }

    // ---- GEMM3: heads = x2 @ [Wm;Wc]^T  [32 x 27], K = 128 padded ----
    f32x4 acc3[2][2];
    #pragma unroll
    for (int t = 0; t < 2; ++t) { acc3[t][0] = (f32x4){0,0,0,0}; acc3[t][1] = (f32x4){0,0,0,0}; }
    #pragma unroll
    for (int ks = 0; ks < 4; ++ks) {
        bf16x8 a0 = *(const bf16x8*)&XsW[ c       * K_STRIDE + ks*32 + q*8];
        bf16x8 a1 = *(const bf16x8*)&XsW[(16 + c) * K_STRIDE + ks*32 + q*8];
        #pragma unroll
        for (int ht = 0; ht < 2; ++ht) {
            bf16x8 bf = *(const bf16x8*)&Whs[(ht*16 + c) * K_STRIDE + ks*32 + q*8];
            acc3[0][ht] = __builtin_amdgcn_mfma_f32_16x16x32_bf16(a0, bf, acc3[0][ht], 0, 0, 0);
            acc3[1][ht] = __builtin_amdgcn_mfma_f32_16x16x32_bf16(a1, bf, acc3[1][ht], 0, 0, 0);
        }
    }

    // ---- epilogue: tanh mean / softplus chol, scattered from C-fragments ----
    #pragma unroll
    for (int ht = 0; ht < 2; ++ht) {
        const int n = ht*16 + c;
        #pragma unroll
        for (int t = 0; t < 2; ++t) {
            const size_t r0 = rowBase + t*16 + q*4;
            if (n < 6) {            // mean (only ht==0 lanes)
                const float bias = bm[n];
                #pragma unroll
                for (int i = 0; i < 4; ++i)
                    out_mean[(r0 + i) * 6 + n] = tanhf(acc3[t][ht][i] + bias);
            } else if (n < HN) {    // chol value
                const float bias = bc[n - 6];
                const int off = CHOFF[n - 6];
                #pragma unroll
                for (int i = 0; i < 4; ++i) {
                    float v = acc3[t][ht][i] + bias;
                    out_chol[(r0 + i) * 36 + off] = fmaxf(v, 0.f) + log1pf(expf(-fabsf(v)));
                }
            }
        }
    }
    // zero the 15 upper-triangle slots of each of this wave's 32 rows
    for (int idx = lane; idx < 32 * 15; idx += 64) {
        int r = idx / 15;
        int o = ZOFF[idx - r * 15];
        out_chol[(rowBase + r) * 36 + o] = 0.f;
    }
}

extern "C" void kernel_launch(void* const* d_in, const int* in_sizes, int n_in,
                              void* d_out, int out_size, void* d_ws, size_t ws_size,
                              hipStream_t stream) {
    const float* states = (const float*)d_in[0];
    const float* W1 = (const float*)d_in[1];
    const float* b1 = (const float*)d_in[2];
    const float* W2 = (const float*)d_in[3];
    const float* b2 = (const float*)d_in[4];
    const float* Wm = (const float*)d_in[5];
    const float* bm = (const float*)d_in[6];
    const float* Wc = (const float*)d_in[7];
    const float* bc = (const float*)d_in[8];

    const int batch = in_sizes[0] / STATE;                  // 262144
    float* out_mean = (float*)d_out;                        // [B,6]
    float* out_chol = out_mean + (size_t)batch * 6;         // [B,6,6]

    // >64 KiB dynamic LDS needs the opt-in attribute (gfx950 allows 160 KiB/WG)
    hipFuncSetAttribute((const void*)actor_mfma,
                        hipFuncAttributeMaxDynamicSharedMemorySize, LDS_BYTES);

    const int grid = batch / 256;                           // 256 rows per block
    actor_mfma<<<grid, 512, LDS_BYTES, stream>>>(states, W1, b1, W2, b2,
                                                 Wm, bm, Wc, bc,
                                                 out_mean, out_chol);
}

// Round 3
// 119.995 us; speedup vs baseline: 3.3150x; 1.4009x over previous
//
#include <hip/hip_runtime.h>
#include <hip/hip_bf16.h>
#include <math.h>

typedef short bf16x8 __attribute__((ext_vector_type(8)));
typedef float f32x4 __attribute__((ext_vector_type(4)));

#define STATE 24
#define L1N 100

// ---- padded bf16 weight image (u16 units), built once per launch in d_ws ----
// strides: bytes %16==0 and (bytes/16) odd -> balanced LDS b128 slot usage
#define W1_STRIDE 40              // K 24 -> pad 40 halves (80 B)
#define K_STRIDE 136              // K 100 -> pad 136 halves (272 B)
#define W1_OFF 0                  // 100 rows x 40
#define W2_OFF 4000               // 100 rows x 136
#define WH_OFF 17600              // 27 rows x 136 (6 mean + 21 chol)
#define IMG_U32 10752             // 21272 halves padded to 21504 (43008 B)
#define IMG_BYTES (IMG_U32 * 4)

#define X_HALVES 2176             // per-wave X: 16 rows x 136
#define NWAVES 8
#define LDS_BYTES (IMG_BYTES + NWAVES * X_HALVES * 2)   // 77824 B -> 2 blocks/CU

__device__ __constant__ int CHOFF[21] = {0,6,7,12,13,14,18,19,20,21,24,25,26,27,28,30,31,32,33,34,35};
__device__ __constant__ int ZOFF[15]  = {1,2,3,4,5,8,9,10,11,15,16,17,22,23,29};

__device__ inline unsigned short f2bf(float f) {
    union { float f; unsigned u; } v; v.f = f;
    unsigned r = v.u + 0x7FFFu + ((v.u >> 16) & 1u);   // RNE
    return (unsigned short)(r >> 16);
}
__device__ inline unsigned pkbf(float lo, float hi) {
    __hip_bfloat162 h = __float22bfloat162_rn(float2{lo, hi});
    return *(const unsigned*)&h;
}
// tanh(x) = 1 - 2/(e^{2x}+1), via v_exp_f32 + v_rcp_f32 (~5 ops, |err|~1e-7)
__device__ inline float fast_tanh(float x) {
    float e = __builtin_amdgcn_exp2f(x * 2.8853900817779268f);   // e^{2x}
    return 1.0f - 2.0f * __builtin_amdgcn_rcpf(e + 1.0f);
}
// softplus(v) = max(v,0) + ln(1+e^{-|v|}), via v_exp/v_log (~7 ops)
__device__ inline float fast_softplus(float v) {
    float u = __builtin_amdgcn_exp2f(fabsf(v) * -1.4426950408889634f);
    float l = __builtin_amdgcn_logf(1.0f + u) * 0.6931471805599453f;
    return fmaxf(v, 0.0f) + l;
}

// ---- prologue: build padded bf16 weight image in workspace ----
__global__ __launch_bounds__(256) void prep_weights(
    const float* __restrict__ W1, const float* __restrict__ W2,
    const float* __restrict__ Wm, const float* __restrict__ Wc,
    unsigned* __restrict__ img)
{
    int i = blockIdx.x * 256 + threadIdx.x;    // u32 index in image
    if (i >= IMG_U32) return;
    float lo = 0.f, hi = 0.f;
    if (i < 2000) {                            // W1: 100 rows x 20 u32
        int r = i / 20, k = (i % 20) * 2;
        if (k < STATE)     lo = W1[r * STATE + k];
        if (k + 1 < STATE) hi = W1[r * STATE + k + 1];
    } else if (i < 8800) {                     // W2: 100 rows x 68 u32
        int j = i - 2000, r = j / 68, k = (j % 68) * 2;
        if (k < L1N)     lo = W2[r * L1N + k];
        if (k + 1 < L1N) hi = W2[r * L1N + k + 1];
    } else if (i < 10636) {                    // [Wm;Wc]: 27 rows x 68 u32
        int j = i - 8800, r = j / 68, k = (j % 68) * 2;
        const float* src = (r < 6) ? (Wm + r * L1N) : (Wc + (r - 6) * L1N);
        if (k < L1N)     lo = src[k];
        if (k + 1 < L1N) hi = src[k + 1];
    }                                          // else: zero pad tail
    img[i] = pkbf(lo, hi);
}

__global__ __launch_bounds__(512, 4) void actor_mfma(
    const float* __restrict__ states,
    const unsigned* __restrict__ img,
    const float* __restrict__ b1, const float* __restrict__ b2,
    const float* __restrict__ bm, const float* __restrict__ bc,
    float* __restrict__ out_mean, float* __restrict__ out_chol)
{
    extern __shared__ __align__(16) unsigned short smem[];
    unsigned short* W1s = smem + W1_OFF;
    unsigned short* W2s = smem + W2_OFF;
    unsigned short* Whs = smem + WH_OFF;
    const int tid = threadIdx.x;

    // stage prebuilt bf16 image: plain coalesced b128 copy (no conversion)
    {
        const uint4* src = (const uint4*)img;
        uint4* dst = (uint4*)smem;
        for (int i = tid; i < IMG_BYTES / 16; i += 512)
            dst[i] = src[i];
    }

    const int wave = tid >> 6, lane = tid & 63;
    unsigned short* XsW = smem + IMG_U32 * 2 + wave * X_HALVES;
    {   // zero K-pad cols 96..135 of own-wave X (320 u32 total)
        unsigned* xz = (unsigned*)XsW;
        #pragma unroll
        for (int it = 0; it < 5; ++it) {
            int idx = it * 64 + lane;          // 0..319
            int r = idx / 20, s = idx - r * 20;
            xz[r * 68 + 48 + s] = 0u;
        }
    }
    __syncthreads();

    const int q = lane >> 4, c = lane & 15;
    const long rowBase = (long)blockIdx.x * 128 + wave * 16;

    // ---- GEMM1: x1 = relu(states @ W1^T + b1), one 16-row m-tile ----
    union { bf16x8 v; unsigned u[4]; } af;
    af.u[0] = af.u[1] = af.u[2] = af.u[3] = 0;
    if (q < 3) {
        const float* p = states + (rowBase + c) * STATE + q * 8;
        float4 v0 = *(const float4*)p;
        float4 v1 = *(const float4*)(p + 4);
        af.u[0] = pkbf(v0.x, v0.y); af.u[1] = pkbf(v0.z, v0.w);
        af.u[2] = pkbf(v1.x, v1.y); af.u[3] = pkbf(v1.z, v1.w);
    }
    #pragma unroll
    for (int nt = 0; nt < 7; ++nt) {
        const int n = nt * 16 + c;
        const int cl = n < L1N ? n : L1N - 1;  // clamp: garbage cols discarded
        bf16x8 bfrag = *(const bf16x8*)&W1s[cl * W1_STRIDE + q * 8];
        const float bias = b1[cl];
        f32x4 acc = {bias, bias, bias, bias};
        acc = __builtin_amdgcn_mfma_f32_16x16x32_bf16(af.v, bfrag, acc, 0, 0, 0);
        if (n < L1N) {
            #pragma unroll
            for (int i = 0; i < 4; ++i)        // C: row=q*4+i, col=c
                XsW[(q * 4 + i) * K_STRIDE + n] = f2bf(fmaxf(acc[i], 0.f));
        }
    }

    // ---- GEMM2: x2 = relu(x1 @ W2^T + b2), K=128 padded ----
    bf16x8 a2[4];
    #pragma unroll
    for (int ks = 0; ks < 4; ++ks)             // reads precede in-place writes
        a2[ks] = *(const bf16x8*)&XsW[c * K_STRIDE + ks * 32 + q * 8];
    f32x4 acc2[7];
    #pragma unroll
    for (int nt = 0; nt < 7; ++nt) {
        const int n = nt * 16 + c;
        const float bias = b2[n < L1N ? n : L1N - 1];
        acc2[nt] = (f32x4){bias, bias, bias, bias};
    }
    #pragma unroll
    for (int ks = 0; ks < 4; ++ks) {
        #pragma unroll
        for (int nt = 0; nt < 7; ++nt) {
            const int cl = (nt * 16 + c) < L1N ? (nt * 16 + c) : L1N - 1;
            bf16x8 bfrag = *(const bf16x8*)&W2s[cl * K_STRIDE + ks * 32 + q * 8];
            acc2[nt] = __builtin_amdgcn_mfma_f32_16x16x32_bf16(a2[ks], bfrag, acc2[nt], 0, 0, 0);
        }
    }
    #pragma unroll
    for (int nt = 0; nt < 7; ++nt) {
        const int n = nt * 16 + c;
        if (n < L1N) {
            #pragma unroll
            for (int i = 0; i < 4; ++i)
                XsW[(q * 4 + i) * K_STRIDE + n] = f2bf(fmaxf(acc2[nt][i], 0.f));
        }
    }

    // ---- GEMM3: heads = x2 @ [Wm;Wc]^T, 27 outs in 2 n-tiles ----
    bf16x8 a3[4];
    #pragma unroll
    for (int ks = 0; ks < 4; ++ks)
        a3[ks] = *(const bf16x8*)&XsW[c * K_STRIDE + ks * 32 + q * 8];
    const float bias0 = (c < 6) ? bm[c] : bc[c - 6];
    const float bias1 = bc[(c + 10) < 21 ? (c + 10) : 20];
    f32x4 acc3[2] = {{bias0, bias0, bias0, bias0}, {bias1, bias1, bias1, bias1}};
    #pragma unroll
    for (int ks = 0; ks < 4; ++ks) {
        #pragma unroll
        for (int ht = 0; ht < 2; ++ht) {
            const int cl = (ht * 16 + c) < 27 ? (ht * 16 + c) : 26;
            bf16x8 bfrag = *(const bf16x8*)&Whs[cl * K_STRIDE + ks * 32 + q * 8];
            acc3[ht] = __builtin_amdgcn_mfma_f32_16x16x32_bf16(a3[ks], bfrag, acc3[ht], 0, 0, 0);
        }
    }

    // ---- epilogue ----
    if (c < 6) {                               // mean: n = c
        #pragma unroll
        for (int i = 0; i < 4; ++i)
            out_mean[(rowBase + q * 4 + i) * 6 + c] = fast_tanh(acc3[0][i]);
    } else {                                   // chol idx c-6 (0..9)
        const int off = CHOFF[c - 6];
        #pragma unroll
        for (int i = 0; i < 4; ++i)
            out_chol[(rowBase + q * 4 + i) * 36 + off] = fast_softplus(acc3[0][i]);
    }
    if (c < 11) {                              // chol idx c+10 (10..20)
        const int off = CHOFF[c + 10];
        #pragma unroll
        for (int i = 0; i < 4; ++i)
            out_chol[(rowBase + q * 4 + i) * 36 + off] = fast_softplus(acc3[1][i]);
    }
    #pragma unroll
    for (int it = 0; it < 4; ++it) {           // zero 15 upper-tri slots x 16 rows
        int idx = it * 64 + lane;
        if (idx < 240) {
            int r = idx / 15, o = ZOFF[idx - r * 15];
            out_chol[(rowBase + r) * 36 + o] = 0.f;
        }
    }
}

extern "C" void kernel_launch(void* const* d_in, const int* in_sizes, int n_in,
                              void* d_out, int out_size, void* d_ws, size_t ws_size,
                              hipStream_t stream) {
    const float* states = (const float*)d_in[0];
    const float* W1 = (const float*)d_in[1];
    const float* b1 = (const float*)d_in[2];
    const float* W2 = (const float*)d_in[3];
    const float* b2 = (const float*)d_in[4];
    const float* Wm = (const float*)d_in[5];
    const float* bm = (const float*)d_in[6];
    const float* Wc = (const float*)d_in[7];
    const float* bc = (const float*)d_in[8];

    const int batch = in_sizes[0] / STATE;                  // 262144
    float* out_mean = (float*)d_out;                        // [B,6]
    float* out_chol = out_mean + (size_t)batch * 6;         // [B,6,6]
    unsigned* img = (unsigned*)d_ws;                        // 43008 B bf16 image

    hipFuncSetAttribute((const void*)actor_mfma,
                        hipFuncAttributeMaxDynamicSharedMemorySize, LDS_BYTES);

    prep_weights<<<(IMG_U32 + 255) / 256, 256, 0, stream>>>(W1, W2, Wm, Wc, img);
    actor_mfma<<<batch / 128, 512, LDS_BYTES, stream>>>(states, img, b1, b2, bm, bc,
                                                        out_mean, out_chol);
}